// Round 6
// baseline (303.634 us; speedup 1.0000x reference)
//
#include <hip/hip_runtime.h>
#include <hip/hip_bf16.h>
#include <cstdint>

// MFVI second-order CRF, B=32 S=1024 T=256 W=2 ITER=3.
// msg = Shift(P) @ Wc, M=32768 N=256 K=1024 (4 shift regions).
// Round 6: M-tile 128 (grid 256, 1 block/CU), Ps resident per K-quarter,
// double-buffered 32-k Bs slices with DMA prefetch under MFMA compute.
// Timed window includes ~154us of harness ws-poison fills (fixed floor).
//
// ws: Pa bf16 [32][1028][256] @0 | Pb @32MB | WcT bf16 [256][1024] @64MB

typedef __attribute__((ext_vector_type(4))) float f32x4;
typedef __attribute__((ext_vector_type(8))) short bf16x8;

__device__ __forceinline__ void load_lds16(const void* g, void* l) {
    __builtin_amdgcn_global_load_lds(
        (const __attribute__((address_space(1))) void*)g,
        (__attribute__((address_space(3))) void*)l, 16, 0, 0);
}

// ---------------- phase-0 helpers ------------------------------------------
__device__ __forceinline__ void wct_one(const float* __restrict__ trans,
                                        __hip_bfloat16* __restrict__ wct, int e) {
    int n = e >> 10, k = e & 1023;
    int r = k >> 8, kk = k & 255;
    float v;
    if (r == 0)      v = trans[kk * 256 + n];
    else if (r == 1) v = trans[65536 + kk * 256 + n];
    else if (r == 2) v = trans[n * 256 + kk];
    else             v = trans[65536 + n * 256 + kk];
    wct[n * 1024 + k] = __float2bfloat16(v);
}

__device__ __forceinline__ void guard_one(__hip_bfloat16* Pa, __hip_bfloat16* Pb, int g) {
    __hip_bfloat16* P = (g & 32768) ? Pb : Pa;
    int rem = g & 32767;
    int b = rem >> 10, wr = (rem >> 8) & 3, col = rem & 255;
    int row = b * 1028 + ((wr < 2) ? wr : 1024 + wr);   // 0,1,1026,1027
    P[row * 256 + col] = __float2bfloat16(0.f);
}

__device__ __forceinline__ void softmax0_row(const float* __restrict__ unary,
                                             const int* __restrict__ lengths,
                                             __hip_bfloat16* __restrict__ Pa,
                                             int row, int lane) {
    int b = row >> 10, s = row & 1023;
    float mval = (s < lengths[b]) ? 1.f : 0.f;
    float4 x = *((const float4*)(unary + (size_t)row * 256 + lane * 4));
    x.x *= mval; x.y *= mval; x.z *= mval; x.w *= mval;
    float mx = fmaxf(fmaxf(x.x, x.y), fmaxf(x.z, x.w));
    #pragma unroll
    for (int o = 32; o; o >>= 1) mx = fmaxf(mx, __shfl_xor(mx, o));
    float ea = __expf(x.x - mx), eb = __expf(x.y - mx);
    float ec = __expf(x.z - mx), ed = __expf(x.w - mx);
    float sum = ea + eb + ec + ed;
    #pragma unroll
    for (int o = 32; o; o >>= 1) sum += __shfl_xor(sum, o);
    float inv = 1.0f / sum;
    union { ushort4 u; __hip_bfloat16 h[4]; } o4;
    o4.h[0] = __float2bfloat16(ea * inv);
    o4.h[1] = __float2bfloat16(eb * inv);
    o4.h[2] = __float2bfloat16(ec * inv);
    o4.h[3] = __float2bfloat16(ed * inv);
    *((ushort4*)(Pa + ((size_t)b * 1028 + 2 + s) * 256 + lane * 4)) = o4.u;
}

__global__ __launch_bounds__(256) void prep_softmax0(
    const float* __restrict__ unary, const float* __restrict__ trans,
    const int* __restrict__ lengths,
    __hip_bfloat16* __restrict__ Pa, __hip_bfloat16* __restrict__ Pb,
    __hip_bfloat16* __restrict__ WcT)
{
    int tid = threadIdx.x, lane = tid & 63, wid = tid >> 6;
    int blk = blockIdx.x;                      // 0..511
    int e0 = (blk * 256 + tid) * 2;
    wct_one(trans, WcT, e0);
    wct_one(trans, WcT, e0 + 1);
    int idx = blk * 256 + tid;
    if (idx < 65536) guard_one(Pa, Pb, idx);
    for (int q = 0; q < 16; ++q)
        softmax0_row(unary, lengths, Pa, blk * 64 + wid * 16 + q, lane);
}

// ---------------- iteration kernel -----------------------------------------
// 512 threads = 8 waves as 2(M) x 4(N): wave w covers rows (w>>2)*64..+63,
// cols (w&3)*64..+63; acc 4x4 f32x4. M-tile 128, grid 256 (1 block/CU).
// K = 32 phases of 32-k. Ps: one K-quarter (132 rows x 64 cols) resident;
// Bs: two 16 KB buffers, phase f+1 DMA'd under phase f's MFMAs.
__global__ __launch_bounds__(512, 2) void mfvi_iter_k(
    const __hip_bfloat16* __restrict__ Pin,   // [32][1028][256] padded
    const __hip_bfloat16* __restrict__ WcT,   // [256][1024]
    const float* __restrict__ unary, const int* __restrict__ lengths,
    const float* __restrict__ startT, const float* __restrict__ endT,
    __hip_bfloat16* __restrict__ Pout, float* __restrict__ out, int final_it)
{
    __shared__ __hip_bfloat16 Ps[132 * 64];      // 16896 B (8 chunks/row)
    __shared__ __hip_bfloat16 Bs[2][256 * 32];   // 2 x 16384 B (4 chunks/row)
    __shared__ float redA[512];                  // [nslice][row 0..127]
    __shared__ float redB[512];

    int tid = threadIdx.x;
    int lane = tid & 63, w = tid >> 6;
    int cn = lane & 15, quad = lane >> 4;
    int wm = (w >> 2) << 6, wn = (w & 3) << 6;
    int nslice = w & 3;
    int blk = blockIdx.x;
    int b = blk >> 3, mt = blk & 7;
    int s0 = mt << 7;
    int len = lengths[b];
    const char* PbaseB = (const char*)(Pin + ((size_t)b * 1028 + s0) * 256);

    f32x4 acc[4][4] = {};

    // --- staging helpers (slot<->global-chunk XOR swizzles keep ds_read_b128
    //     at <=2-way bank aliasing, which is free) ---
    auto stagePs = [&](int q) {      // quarter q: P cols q*64..+63, rows 0..131
        #pragma unroll
        for (int t = 0; t < 2; ++t) {
            int s = t * 512 + tid;
            int r = s >> 3, ch = s & 7, g = ch ^ (r & 7);
            load_lds16(PbaseB + r * 512 + q * 128 + g * 16, (char*)Ps + s * 16);
        }
        if (tid < 32) {
            int s = 1024 + tid;
            int r = s >> 3, ch = s & 7, g = ch ^ (r & 7);
            load_lds16(PbaseB + r * 512 + q * 128 + g * 16, (char*)Ps + s * 16);
        }
    };
    auto stageBs = [&](int f) {      // phase f: WcT[:, region*256+q*64+hs*32 ..+31]
        int q = f >> 3, region = (f >> 1) & 3, hs = f & 1;
        int koff = region * 256 + q * 64 + hs * 32;
        char* buf = (char*)Bs[f & 1];
        #pragma unroll
        for (int c = 0; c < 2; ++c) {
            int s = c * 512 + tid;
            int n = s >> 2, ch = s & 3, g = ch ^ (n & 3);
            load_lds16((const char*)(WcT + n * 1024 + koff) + g * 16, buf + s * 16);
        }
    };

    stagePs(0);
    stageBs(0);
    __syncthreads();

    for (int f = 0; f < 32; ++f) {
        int p = f & 7;
        if (f < 31 && p != 7) stageBs(f + 1);   // prefetch under compute
        if (f < 31 && p == 7) stageBs(f + 1);   // also prefetch (buffer is free)

        int region = (f >> 1) & 3, hs = f & 1;
        int delta = (region == 0) ? -1 : (region == 1) ? -2
                  : (region == 2) ?  1 : 2;
        const char* bbuf = (const char*)Bs[f & 1];

        bf16x8 af[4], bfv[4];
        #pragma unroll
        for (int i = 0; i < 4; ++i) {
            int r = wm + (i << 4) + cn + delta + 2;      // 0..131
            int g = hs * 4 + quad;                        // chunk 0..7
            int slot = g ^ (r & 7);
            af[i] = *(const bf16x8*)((const char*)Ps + r * 128 + slot * 16);
        }
        #pragma unroll
        for (int j = 0; j < 4; ++j) {
            int n = wn + (j << 4) + cn;
            bfv[j] = *(const bf16x8*)(bbuf + n * 64 + ((quad ^ (n & 3)) << 4));
        }
        #pragma unroll
        for (int i = 0; i < 4; ++i)
            #pragma unroll
            for (int j = 0; j < 4; ++j)
                acc[i][j] = __builtin_amdgcn_mfma_f32_16x16x32_bf16(
                    af[i], bfv[j], acc[i][j], 0, 0, 0);

        if (f < 31) {
            if (p == 7) {
                __syncthreads();                 // compute f done -> Ps free
                stagePs((f + 1) >> 3);           // re-stage Ps for next quarter
                __syncthreads();                 // drain Ps (+ Bs f+1)
            } else {
                __syncthreads();                 // drain prefetched Bs f+1
            }
        }
    }

    // --- epilogue: boundary + unary + mask. C/D: col=lane&15, row=quad*4+reg
    #pragma unroll
    for (int i = 0; i < 4; ++i)
        #pragma unroll
        for (int j = 0; j < 4; ++j) {
            int n = wn + (j << 4) + cn;
            #pragma unroll
            for (int r = 0; r < 4; ++r) {
                int s = s0 + wm + (i << 4) + (quad << 2) + r;
                float x = acc[i][j][r];
                if (s == 0)       x += startT[n];
                if (s == 1)       x += startT[256 + n];
                if (s == len - 1) x += endT[n];
                if (s == len - 2) x += endT[256 + n];
                long idx = ((long)((b << 10) + s)) * 256 + n;
                x += unary[idx];
                acc[i][j][r] = (s < len) ? x : 0.f;
            }
        }

    if (final_it) {
        #pragma unroll
        for (int i = 0; i < 4; ++i)
            #pragma unroll
            for (int j = 0; j < 4; ++j) {
                int n = wn + (j << 4) + cn;
                #pragma unroll
                for (int r = 0; r < 4; ++r) {
                    int s = s0 + wm + (i << 4) + (quad << 2) + r;
                    out[((long)((b << 10) + s)) * 256 + n] = acc[i][j][r];
                }
            }
        return;
    }

    // --- fused row softmax over 256 cols: quad shfl-reduce then 4-nslice
    // LDS combine. redA[nslice*128 + row]
    __syncthreads();   // all waves past K-loop before red arrays cycle
    #pragma unroll
    for (int i = 0; i < 4; ++i)
        #pragma unroll
        for (int r = 0; r < 4; ++r) {
            float m4 = fmaxf(fmaxf(acc[i][0][r], acc[i][1][r]),
                             fmaxf(acc[i][2][r], acc[i][3][r]));
            m4 = fmaxf(m4, __shfl_xor(m4, 1));
            m4 = fmaxf(m4, __shfl_xor(m4, 2));
            m4 = fmaxf(m4, __shfl_xor(m4, 4));
            m4 = fmaxf(m4, __shfl_xor(m4, 8));
            if (cn == 0)
                redA[(nslice << 7) + wm + (i << 4) + (quad << 2) + r] = m4;
        }
    __syncthreads();
    float M[4][4];
    #pragma unroll
    for (int i = 0; i < 4; ++i)
        #pragma unroll
        for (int r = 0; r < 4; ++r) {
            int row = wm + (i << 4) + (quad << 2) + r;
            M[i][r] = fmaxf(fmaxf(redA[row], redA[128 + row]),
                            fmaxf(redA[256 + row], redA[384 + row]));
        }
    #pragma unroll
    for (int i = 0; i < 4; ++i)
        #pragma unroll
        for (int r = 0; r < 4; ++r) {
            float s4 = 0.f;
            #pragma unroll
            for (int j = 0; j < 4; ++j) {
                float e = __expf(acc[i][j][r] - M[i][r]);
                acc[i][j][r] = e;
                s4 += e;
            }
            s4 += __shfl_xor(s4, 1);
            s4 += __shfl_xor(s4, 2);
            s4 += __shfl_xor(s4, 4);
            s4 += __shfl_xor(s4, 8);
            if (cn == 0)
                redB[(nslice << 7) + wm + (i << 4) + (quad << 2) + r] = s4;
        }
    __syncthreads();
    #pragma unroll
    for (int i = 0; i < 4; ++i)
        #pragma unroll
        for (int r = 0; r < 4; ++r) {
            int row = wm + (i << 4) + (quad << 2) + r;
            float inv = 1.0f / (redB[row] + redB[128 + row] +
                                redB[256 + row] + redB[384 + row]);
            int s = s0 + row;
            #pragma unroll
            for (int j = 0; j < 4; ++j) {
                int n = wn + (j << 4) + cn;
                Pout[((size_t)b * 1028 + 2 + s) * 256 + n] =
                    __float2bfloat16(acc[i][j][r] * inv);
            }
        }
}

extern "C" void kernel_launch(void* const* d_in, const int* in_sizes, int n_in,
                              void* d_out, int out_size, void* d_ws, size_t ws_size,
                              hipStream_t stream) {
    const float* unary  = (const float*)d_in[1];
    const float* trans  = (const float*)d_in[3];
    const float* startT = (const float*)d_in[4];
    const float* endT   = (const float*)d_in[5];
    const int*   lens   = (const int*)d_in[6];

    char* ws = (char*)d_ws;
    __hip_bfloat16* Pa  = (__hip_bfloat16*)ws;                          // 16.8 MB
    __hip_bfloat16* Pb  = (__hip_bfloat16*)(ws + ((size_t)32 << 20));   // 16.8 MB
    __hip_bfloat16* WcT = (__hip_bfloat16*)(ws + ((size_t)64 << 20));   // 512 KB
    float* out = (float*)d_out;

    prep_softmax0<<<dim3(512), dim3(256), 0, stream>>>(unary, trans, lens, Pa, Pb, WcT);
    mfvi_iter_k<<<dim3(256), dim3(512), 0, stream>>>(Pa, WcT, unary, lens, startT, endT, Pb, nullptr, 0);
    mfvi_iter_k<<<dim3(256), dim3(512), 0, stream>>>(Pb, WcT, unary, lens, startT, endT, Pa, nullptr, 0);
    mfvi_iter_k<<<dim3(256), dim3(512), 0, stream>>>(Pa, WcT, unary, lens, startT, endT, nullptr, out, 1);
}

// Round 7
// 294.370 us; speedup vs baseline: 1.0315x; 1.0315x over previous
//
#include <hip/hip_runtime.h>
#include <hip/hip_bf16.h>
#include <cstdint>

// MFVI second-order CRF, B=32 S=1024 T=256 W=2 ITER=3.
// msg = Shift(P) @ Wc, M=32768 N=256 K=1024 (4 shift regions).
// Round 7: barrier-free K-loop. B pre-swizzled into MFMA fragment order
// (Wfrag, 512 KB, L2-resident) -> coalesced register-direct loads, no Bs LDS,
// no staging barriers. Full A-slice (68x256) DMA-staged once per block.
// Timed window includes ~155us of harness ws-poison fills (fixed floor).
//
// ws: Pa bf16 [32][1028][256] @0 | Pb @32MB | Wfrag bf16 [32][16][64][8] @64MB

typedef __attribute__((ext_vector_type(4))) float f32x4;
typedef __attribute__((ext_vector_type(8))) short bf16x8;

__device__ __forceinline__ void load_lds16(const void* g, void* l) {
    __builtin_amdgcn_global_load_lds(
        (const __attribute__((address_space(1))) void*)g,
        (__attribute__((address_space(3))) void*)l, 16, 0, 0);
}

// ---------------- phase-0 helpers ------------------------------------------
// Wfrag[c][jp][lane][e]: B-fragment value for kchunk c (32-k), n = jp*16+
// (lane&15), k = c*32 + (lane>>4)*8 + e. region=c>>3, kr=k within region.
__device__ __forceinline__ void wfrag_one(const float* __restrict__ trans,
                                          __hip_bfloat16* __restrict__ wfrag,
                                          int gid) {
    int c = gid >> 10, jp = (gid >> 6) & 15, l = gid & 63;
    int region = c >> 3;
    int n = jp * 16 + (l & 15);
    int kr0 = (c & 7) * 32 + (l >> 4) * 8;
    union { ushort4 u[2]; __hip_bfloat16 h[8]; } o;
    #pragma unroll
    for (int e = 0; e < 8; ++e) {
        int kr = kr0 + e;
        float v;
        if (region == 0)      v = trans[kr * 256 + n];
        else if (region == 1) v = trans[65536 + kr * 256 + n];
        else if (region == 2) v = trans[n * 256 + kr];
        else                  v = trans[65536 + n * 256 + kr];
        o.h[e] = __float2bfloat16(v);
    }
    *((uint4*)(wfrag + (size_t)gid * 8)) = *((uint4*)&o);
}

__device__ __forceinline__ void guard_one(__hip_bfloat16* Pa, __hip_bfloat16* Pb, int g) {
    __hip_bfloat16* P = (g & 32768) ? Pb : Pa;
    int rem = g & 32767;
    int b = rem >> 10, wr = (rem >> 8) & 3, col = rem & 255;
    int row = b * 1028 + ((wr < 2) ? wr : 1024 + wr);   // 0,1,1026,1027
    P[row * 256 + col] = __float2bfloat16(0.f);
}

__device__ __forceinline__ void softmax0_row(const float* __restrict__ unary,
                                             const int* __restrict__ lengths,
                                             __hip_bfloat16* __restrict__ Pa,
                                             int row, int lane) {
    int b = row >> 10, s = row & 1023;
    float mval = (s < lengths[b]) ? 1.f : 0.f;
    float4 x = *((const float4*)(unary + (size_t)row * 256 + lane * 4));
    x.x *= mval; x.y *= mval; x.z *= mval; x.w *= mval;
    float mx = fmaxf(fmaxf(x.x, x.y), fmaxf(x.z, x.w));
    #pragma unroll
    for (int o = 32; o; o >>= 1) mx = fmaxf(mx, __shfl_xor(mx, o));
    float ea = __expf(x.x - mx), eb = __expf(x.y - mx);
    float ec = __expf(x.z - mx), ed = __expf(x.w - mx);
    float sum = ea + eb + ec + ed;
    #pragma unroll
    for (int o = 32; o; o >>= 1) sum += __shfl_xor(sum, o);
    float inv = 1.0f / sum;
    union { ushort4 u; __hip_bfloat16 h[4]; } o4;
    o4.h[0] = __float2bfloat16(ea * inv);
    o4.h[1] = __float2bfloat16(eb * inv);
    o4.h[2] = __float2bfloat16(ec * inv);
    o4.h[3] = __float2bfloat16(ed * inv);
    *((ushort4*)(Pa + ((size_t)b * 1028 + 2 + s) * 256 + lane * 4)) = o4.u;
}

__global__ __launch_bounds__(256) void prep_softmax0(
    const float* __restrict__ unary, const float* __restrict__ trans,
    const int* __restrict__ lengths,
    __hip_bfloat16* __restrict__ Pa, __hip_bfloat16* __restrict__ Pb,
    __hip_bfloat16* __restrict__ Wfrag)
{
    int tid = threadIdx.x, lane = tid & 63, wid = tid >> 6;
    int blk = blockIdx.x;                      // 0..511
    int idx = blk * 256 + tid;
    if (blk < 128) wfrag_one(trans, Wfrag, idx);      // 32768 frag-lines
    if (idx < 65536) guard_one(Pa, Pb, idx);
    for (int q = 0; q < 16; ++q)
        softmax0_row(unary, lengths, Pa, blk * 64 + wid * 16 + q, lane);
}

// ---------------- iteration kernel -----------------------------------------
// Block 256 = 4 waves; M-tile 64 (grid 512); wave w owns all 64 rows x cols
// w*64..+63. Ps = P rows s0-2..s0+65 x 256 cols resident in LDS (staged once).
// K-loop: 32 kchunks, B-frags register-direct from Wfrag (coalesced, L2),
// ZERO barriers inside the loop.
__global__ __launch_bounds__(256, 3) void mfvi_iter_k(
    const __hip_bfloat16* __restrict__ Pin,   // [32][1028][256] padded
    const __hip_bfloat16* __restrict__ Wfrag, // [32][16][64][8]
    const float* __restrict__ unary, const int* __restrict__ lengths,
    const float* __restrict__ startT, const float* __restrict__ endT,
    __hip_bfloat16* __restrict__ Pout, float* __restrict__ out, int final_it)
{
    __shared__ __hip_bfloat16 Ps[68 * 256];   // 34816 B, 32 chunks/row
    __shared__ float redA[256];
    __shared__ float redB[256];

    int tid = threadIdx.x;
    int lane = tid & 63, wid = tid >> 6;
    int cn = lane & 15, quad = lane >> 4;
    int wn = wid << 6, wq = wid << 2;
    int blk = blockIdx.x;
    int b = blk >> 4, s0 = (blk & 15) << 6;
    int len = lengths[b];
    const char* PbaseB = (const char*)(Pin + ((size_t)b * 1028 + s0) * 256);

    // ---- stage Ps once: 68 rows x 32 chunks = 2176 x 16B; LDS slot
    // cid=row*32+sl holds global chunk (sl&~7)|((sl^row)&7) ----
    #pragma unroll
    for (int t = 0; t < 8; ++t) {
        int cid = t * 256 + tid;
        int row = cid >> 5, sl = cid & 31;
        int g = (sl & ~7) | ((sl ^ row) & 7);
        load_lds16(PbaseB + row * 512 + g * 16, (char*)Ps + cid * 16);
    }
    if (tid < 128) {
        int cid = 2048 + tid;
        int row = cid >> 5, sl = cid & 31;
        int g = (sl & ~7) | ((sl ^ row) & 7);
        load_lds16(PbaseB + row * 512 + g * 16, (char*)Ps + cid * 16);
    }
    __syncthreads();

    f32x4 acc[4][4] = {};
    const bf16x8* Wf = (const bf16x8*)Wfrag;

    bf16x8 bcur[4], bnxt[4];
    #pragma unroll
    for (int j = 0; j < 4; ++j)
        bcur[j] = Wf[(size_t)(wq + j) * 64 + lane];

    #pragma unroll 4
    for (int c = 0; c < 32; ++c) {
        if (c < 31) {
            #pragma unroll
            for (int j = 0; j < 4; ++j)
                bnxt[j] = Wf[(size_t)((c + 1) * 16 + wq + j) * 64 + lane];
        }
        int region = c >> 3;
        int delta = ((region & 2) ? 1 : -1) * ((region & 1) + 1);
        int gch = (c & 7) * 4 + quad;          // global chunk 0..31 of Ps row
        bf16x8 af[4];
        #pragma unroll
        for (int i = 0; i < 4; ++i) {
            int r = (i << 4) + cn + delta + 2;                // 0..67
            int slot = (gch & ~7) | ((gch ^ r) & 7);
            af[i] = *(const bf16x8*)((const char*)Ps + r * 512 + slot * 16);
        }
        #pragma unroll
        for (int i = 0; i < 4; ++i)
            #pragma unroll
            for (int j = 0; j < 4; ++j)
                acc[i][j] = __builtin_amdgcn_mfma_f32_16x16x32_bf16(
                    af[i], bcur[j], acc[i][j], 0, 0, 0);
        #pragma unroll
        for (int j = 0; j < 4; ++j) bcur[j] = bnxt[j];
    }

    // ---- epilogue: boundary + unary + mask. C/D: col=lane&15, row=quad*4+reg
    #pragma unroll
    for (int i = 0; i < 4; ++i)
        #pragma unroll
        for (int j = 0; j < 4; ++j) {
            int n = wn + (j << 4) + cn;
            #pragma unroll
            for (int r = 0; r < 4; ++r) {
                int s = s0 + (i << 4) + (quad << 2) + r;
                float x = acc[i][j][r];
                if (s == 0)       x += startT[n];
                if (s == 1)       x += startT[256 + n];
                if (s == len - 1) x += endT[n];
                if (s == len - 2) x += endT[256 + n];
                long idx = ((long)((b << 10) + s)) * 256 + n;
                x += unary[idx];
                acc[i][j][r] = (s < len) ? x : 0.f;
            }
        }

    if (final_it) {
        #pragma unroll
        for (int i = 0; i < 4; ++i)
            #pragma unroll
            for (int j = 0; j < 4; ++j) {
                int n = wn + (j << 4) + cn;
                #pragma unroll
                for (int r = 0; r < 4; ++r) {
                    int s = s0 + (i << 4) + (quad << 2) + r;
                    out[((long)((b << 10) + s)) * 256 + n] = acc[i][j][r];
                }
            }
        return;
    }

    // ---- fused row softmax over 256 cols: quad shfl-reduce + 4-wave combine
    #pragma unroll
    for (int i = 0; i < 4; ++i)
        #pragma unroll
        for (int r = 0; r < 4; ++r) {
            float m4 = fmaxf(fmaxf(acc[i][0][r], acc[i][1][r]),
                             fmaxf(acc[i][2][r], acc[i][3][r]));
            m4 = fmaxf(m4, __shfl_xor(m4, 1));
            m4 = fmaxf(m4, __shfl_xor(m4, 2));
            m4 = fmaxf(m4, __shfl_xor(m4, 4));
            m4 = fmaxf(m4, __shfl_xor(m4, 8));
            if (cn == 0) redA[(wid << 6) + (i << 4) + (quad << 2) + r] = m4;
        }
    __syncthreads();
    float M[4][4];
    #pragma unroll
    for (int i = 0; i < 4; ++i)
        #pragma unroll
        for (int r = 0; r < 4; ++r) {
            int row = (i << 4) + (quad << 2) + r;
            M[i][r] = fmaxf(fmaxf(redA[row], redA[64 + row]),
                            fmaxf(redA[128 + row], redA[192 + row]));
        }
    #pragma unroll
    for (int i = 0; i < 4; ++i)
        #pragma unroll
        for (int r = 0; r < 4; ++r) {
            float s4 = 0.f;
            #pragma unroll
            for (int j = 0; j < 4; ++j) {
                float e = __expf(acc[i][j][r] - M[i][r]);
                acc[i][j][r] = e;
                s4 += e;
            }
            s4 += __shfl_xor(s4, 1);
            s4 += __shfl_xor(s4, 2);
            s4 += __shfl_xor(s4, 4);
            s4 += __shfl_xor(s4, 8);
            if (cn == 0) redB[(wid << 6) + (i << 4) + (quad << 2) + r] = s4;
        }
    __syncthreads();
    #pragma unroll
    for (int i = 0; i < 4; ++i)
        #pragma unroll
        for (int r = 0; r < 4; ++r) {
            int row = (i << 4) + (quad << 2) + r;
            float inv = 1.0f / (redB[row] + redB[64 + row] +
                                redB[128 + row] + redB[192 + row]);
            int s = s0 + row;
            #pragma unroll
            for (int j = 0; j < 4; ++j) {
                int n = wn + (j << 4) + cn;
                Pout[((size_t)b * 1028 + 2 + s) * 256 + n] =
                    __float2bfloat16(acc[i][j][r] * inv);
            }
        }
}

extern "C" void kernel_launch(void* const* d_in, const int* in_sizes, int n_in,
                              void* d_out, int out_size, void* d_ws, size_t ws_size,
                              hipStream_t stream) {
    const float* unary  = (const float*)d_in[1];
    const float* trans  = (const float*)d_in[3];
    const float* startT = (const float*)d_in[4];
    const float* endT   = (const float*)d_in[5];
    const int*   lens   = (const int*)d_in[6];

    char* ws = (char*)d_ws;
    __hip_bfloat16* Pa    = (__hip_bfloat16*)ws;                          // 16.8 MB
    __hip_bfloat16* Pb    = (__hip_bfloat16*)(ws + ((size_t)32 << 20));   // 16.8 MB
    __hip_bfloat16* Wfrag = (__hip_bfloat16*)(ws + ((size_t)64 << 20));   // 512 KB
    float* out = (float*)d_out;

    prep_softmax0<<<dim3(512), dim3(256), 0, stream>>>(unary, trans, lens, Pa, Pb, Wfrag);
    mfvi_iter_k<<<dim3(512), dim3(256), 0, stream>>>(Pa, Wfrag, unary, lens, startT, endT, Pb, nullptr, 0);
    mfvi_iter_k<<<dim3(512), dim3(256), 0, stream>>>(Pb, Wfrag, unary, lens, startT, endT, Pa, nullptr, 0);
    mfvi_iter_k<<<dim3(512), dim3(256), 0, stream>>>(Pa, Wfrag, unary, lens, startT, endT, nullptr, out, 1);
}